// Round 7
// baseline (249.979 us; speedup 1.0000x reference)
//
#include <hip/hip_runtime.h>
#include <math.h>

#define EPSV 1.1920929e-07f

typedef __attribute__((ext_vector_type(8))) short short8;
typedef __attribute__((ext_vector_type(4))) float f32x4;

__device__ __forceinline__ float bf2f(unsigned short u) {
    union { unsigned int i; float f; } c; c.i = ((unsigned int)u) << 16; return c.f;
}
__device__ __forceinline__ unsigned short f2bf(float f) {
    union { float f; unsigned int i; } c; c.f = f;
    unsigned int r = c.i + 0x7FFFu + ((c.i >> 16) & 1u);   // RNE
    return (unsigned short)(r >> 16);
}
// pack two f32 -> two bf16 (round-half-up) in one u32: low=a, high=b
__device__ __forceinline__ unsigned int pack_bf16_ru(float a, float b) {
    union { float f; unsigned int i; } ca, cb; ca.f = a; cb.f = b;
    return __builtin_amdgcn_perm(cb.i + 0x8000u, ca.i + 0x8000u, 0x07060302u);
}
// async global -> LDS, 16 B per lane (dest = wave-uniform base + lane*16)
__device__ __forceinline__ void async_lds16(const unsigned short* g, unsigned short* l) {
    __builtin_amdgcn_global_load_lds(
        (const __attribute__((address_space(1))) unsigned int*)g,
        (__attribute__((address_space(3))) unsigned int*)l, 16, 0, 0);
}

// ======================================================================
// cast fp32 -> bf16 elementwise. 4 elems/thread.
// ======================================================================
__global__ __launch_bounds__(256) void cast_bf16(
    const float* __restrict__ src, unsigned short* __restrict__ dst, int n)
{
    const int i = (blockIdx.x * 256 + threadIdx.x) * 4;
    if (i >= n) return;
    const float4 v = *(const float4*)&src[i];
    ushort4 o;
    o.x = f2bf(v.x); o.y = f2bf(v.y); o.z = f2bf(v.z); o.w = f2bf(v.w);
    *(ushort4*)&dst[i] = o;
}

// ======================================================================
// transpose + cast: W [K][N] fp32 -> Wt [N][K] bf16. 32x32 tiles.
// ======================================================================
__global__ __launch_bounds__(256) void transpose_cast(
    const float* __restrict__ W, unsigned short* __restrict__ Wt, int K, int N)
{
    __shared__ float tile[32][33];
    const int n0 = blockIdx.x * 32, k0 = blockIdx.y * 32;
    const int r = threadIdx.x >> 3, c4 = (threadIdx.x & 7) * 4;
    const float4 v = *(const float4*)&W[(size_t)(k0 + r) * N + n0 + c4];
    tile[r][c4 + 0] = v.x; tile[r][c4 + 1] = v.y;
    tile[r][c4 + 2] = v.z; tile[r][c4 + 3] = v.w;
    __syncthreads();
    ushort4 o;
    o.x = f2bf(tile[c4 + 0][r]); o.y = f2bf(tile[c4 + 1][r]);
    o.z = f2bf(tile[c4 + 2][r]); o.w = f2bf(tile[c4 + 3][r]);
    *(ushort4*)&Wt[(size_t)(n0 + r) * K + k0 + c4] = o;
}

// ======================================================================
// bf16 MFMA GEMM, m97 structure: C[M,N] = A[M,K] @ Bt[N,K]^T + bias[N]
// 128x128x32 tile; global_load_lds width-16 staging into unpadded
// [128][32] LDS (dest = wave base + lane*16, matched layout).
// ======================================================================
template <bool OUT_BF16>
__global__ __launch_bounds__(256) void gemm_bf16(
    const unsigned short* __restrict__ A,
    const unsigned short* __restrict__ Bt,
    const float* __restrict__ bias,
    void* __restrict__ Cv,
    int M, int N, int K)
{
    __shared__ unsigned short As[128][32];
    __shared__ unsigned short Bs[128][32];
    const int t    = threadIdx.x;
    const int lane = t & 63;
    const int wv   = t >> 6;
    const int wrow = (wv >> 1) * 64;
    const int wcol = (wv & 1) * 64;
    const int m0 = blockIdx.y * 128;
    const int n0 = blockIdx.x * 128;
    const int col  = lane & 15;
    const int quad = lane >> 4;

    const int srow = (wv << 5) + (lane >> 2);     // wv*32 + 0..15
    const int scol = (lane & 3) << 3;             // 0,8,16,24
    const unsigned short* ap0 = A  + (size_t)(m0 + srow) * K + scol;
    const unsigned short* ap1 = ap0 + (size_t)16 * K;
    const unsigned short* bp0 = Bt + (size_t)(n0 + srow) * K + scol;
    const unsigned short* bp1 = bp0 + (size_t)16 * K;
    unsigned short* al0 = &As[srow][scol];
    unsigned short* al1 = &As[srow + 16][scol];
    unsigned short* bl0 = &Bs[srow][scol];
    unsigned short* bl1 = &Bs[srow + 16][scol];

    f32x4 acc[4][4];
    #pragma unroll
    for (int i = 0; i < 4; ++i)
        #pragma unroll
        for (int j = 0; j < 4; ++j)
            acc[i][j] = (f32x4){0.f, 0.f, 0.f, 0.f};

    for (int k0 = 0; k0 < K; k0 += 32) {
        async_lds16(ap0, al0);
        async_lds16(ap1, al1);
        async_lds16(bp0, bl0);
        async_lds16(bp1, bl1);
        ap0 += 32; ap1 += 32; bp0 += 32; bp1 += 32;
        __syncthreads();
        short8 af[4], bf[4];
        #pragma unroll
        for (int mt = 0; mt < 4; ++mt)
            af[mt] = *(const short8*)&As[wrow + mt * 16 + col][quad << 3];
        #pragma unroll
        for (int nt = 0; nt < 4; ++nt)
            bf[nt] = *(const short8*)&Bs[wcol + nt * 16 + col][quad << 3];
        #pragma unroll
        for (int mt = 0; mt < 4; ++mt)
            #pragma unroll
            for (int nt = 0; nt < 4; ++nt)
                acc[mt][nt] = __builtin_amdgcn_mfma_f32_16x16x32_bf16(
                    af[mt], bf[nt], acc[mt][nt], 0, 0, 0);
        __syncthreads();
    }

    const int rowq = quad << 2;
    #pragma unroll
    for (int nt = 0; nt < 4; ++nt) {
        const int n = n0 + wcol + nt * 16 + col;
        const float bv = bias[n];
        #pragma unroll
        for (int mt = 0; mt < 4; ++mt) {
            #pragma unroll
            for (int r = 0; r < 4; ++r) {
                const int m = m0 + wrow + mt * 16 + rowq + r;
                const float v = acc[mt][nt][r] + bv;
                if (OUT_BF16)
                    ((unsigned short*)Cv)[(size_t)m * N + n] = f2bf(v);
                else
                    ((float*)Cv)[(size_t)m * N + n] = v;
            }
        }
    }
}

// ======================================================================
// RMSNorm (D=64) then rotary, in-place on bf16 q/k slices.
// q output pre-scaled by log2e/8 (folds softmax scale -> exp2 domain).
// ======================================================================
__global__ __launch_bounds__(256) void rmsnorm_rope(
    unsigned short* __restrict__ qkv, const float* __restrict__ cosp,
    const float* __restrict__ sinp, int BT, int T)
{
    const int wid  = (blockIdx.x << 2) + (threadIdx.x >> 6);
    const int lane = threadIdx.x & 63;
    const int w  = wid & 1;
    const int h  = (wid >> 1) & 15;
    const int bt = wid >> 5;
    if (bt >= BT) return;
    const int tpos = bt % T;
    const size_t idx = (size_t)bt * 3072 + (w << 10) + (h << 6) + lane;

    const float x = bf2f(qkv[idx]);
    float ss = x * x;
    #pragma unroll
    for (int m = 1; m < 64; m <<= 1) ss += __shfl_xor(ss, m, 64);
    const float rn = rsqrtf(ss * (1.0f / 64.0f) + EPSV);
    const float xn = x * rn;
    const float other = __shfl_xor(xn, 32, 64);
    const float rot = (lane < 32) ? -other : other;
    const float c = cosp[tpos * 64 + lane];
    const float s = sinp[tpos * 64 + lane];
    const float scale = (w == 0) ? 0.18033688011112042f : 1.0f;  // log2e/8
    qkv[idx] = f2bf(fmaf(xn, c, rot * s) * scale);
}

// ======================================================================
// MFMA flash attention. Block = (b,h) x 64 q-rows, 128 threads = 2 waves;
// wave w owns 32 q-rows as two 16-col tiles sharing K/V^T fragment reads.
// V -> V^T transpose fused into staging via v_perm 2x2 bf16 transpose
// (exact bit moves) + packed b32 LDS writes (2-way banks = free).
// S^T = K Q^T (per-lane softmax state, col = q); PV as O^T = V^T P^T.
// exp2-domain softmax (q pre-scaled by log2e/8 in rmsnorm_rope).
// ======================================================================
__global__ __launch_bounds__(128) void flash_attn_mfma(
    const unsigned short* __restrict__ qkv,
    unsigned short* __restrict__ yb,
    int B, int T)
{
    const int bh = blockIdx.x;
    const int b  = bh >> 4, h = bh & 15;
    const int q0 = ((int)gridDim.y - 1 - (int)blockIdx.y) << 6;  // heavy first
    const int t  = threadIdx.x;
    const int lane = t & 63;
    const int w    = t >> 6;          // 0..1
    const int col  = lane & 15;
    const int quad = lane >> 4;

    __shared__ unsigned short Ks [64][72];
    __shared__ unsigned short Vts[64][72];
    __shared__ unsigned short Ps [2][32][72];   // [wave][q-col 0..31][s]

    const unsigned short* qb = qkv + (size_t)b * T * 3072 + (h << 6);
    const unsigned short* kb = qb + 1024;
    const unsigned short* vb = qb + 2048;

    const int qw  = q0 + (w << 5);           // wave's 32-q base
    const int qg[2] = { qw + col, qw + 16 + col };

    // ---- Q B-frags for both col tiles (pre-scaled by log2e/8) ----
    short8 qf[2][2];
    #pragma unroll
    for (int c = 0; c < 2; ++c) {
        const unsigned short* qrow = qb + (size_t)qg[c] * 3072 + (quad << 3);
        qf[c][0] = *(const short8*)&qrow[0];
        qf[c][1] = *(const short8*)&qrow[32];
    }

    f32x4 oacc[2][4];
    #pragma unroll
    for (int c = 0; c < 2; ++c)
        #pragma unroll
        for (int i = 0; i < 4; ++i) oacc[c][i] = (f32x4){0.f, 0.f, 0.f, 0.f};
    float m_i[2] = {-INFINITY, -INFINITY};
    float l_i[2] = {0.f, 0.f};

    // ---- staging maps (hoisted; +64*3072 per kt) ----
    // K: thread t -> row t>>1, 32-col half (t&1)*32  (4 x b128)
    const int ksr = t >> 1, ksc = (t & 1) << 5;
    const unsigned short* kp = kb + (size_t)ksr * 3072 + ksc;
    unsigned short* kw = &Ks[ksr][ksc];
    // V: thread t -> s-pair sp = t&31, d-chunk dc = (t>>5)*16
    const int sp = t & 31, dc = (t >> 5) << 4;
    const unsigned short* vp = vb + (size_t)(2 * sp) * 3072 + dc;
    const int sp2 = sp << 1;

    unsigned short* pw = &Ps[w][col][0];     // col tile c: +16*72

    const int last_kt = q0 >> 6;
    for (int kt = 0; kt <= last_kt; ++kt) {
        __syncthreads();   // prev compute done reading LDS
        // ---- stage K (straight b128 copy) ----
        *(short8*)&kw[0]  = *(const short8*)&kp[0];
        *(short8*)&kw[8]  = *(const short8*)&kp[8];
        *(short8*)&kw[16] = *(const short8*)&kp[16];
        *(short8*)&kw[24] = *(const short8*)&kp[24];
        // ---- stage V^T (2x2 perm transpose, packed b32 writes) ----
        {
            union { uint4 v[2]; unsigned int u[8]; } R0, R1;
            R0.v[0] = *(const uint4*)&vp[0];
            R0.v[1] = *(const uint4*)&vp[8];
            R1.v[0] = *(const uint4*)&vp[3072];
            R1.v[1] = *(const uint4*)&vp[3080];
            #pragma unroll
            for (int j = 0; j < 8; ++j) {
                const unsigned int lo = __builtin_amdgcn_perm(R1.u[j], R0.u[j], 0x05040100u);
                const unsigned int hi = __builtin_amdgcn_perm(R1.u[j], R0.u[j], 0x07060302u);
                *(unsigned int*)&Vts[dc + 2 * j][sp2]     = lo;
                *(unsigned int*)&Vts[dc + 2 * j + 1][sp2] = hi;
            }
        }
        kp += (size_t)64 * 3072;
        vp += (size_t)64 * 3072;
        __syncthreads();

        // ---- K frags (shared by both col tiles) ----
        short8 kf[2][4];
        #pragma unroll
        for (int ks = 0; ks < 2; ++ks)
            #pragma unroll
            for (int mt = 0; mt < 4; ++mt)
                kf[ks][mt] = *(const short8*)&Ks[mt * 16 + col][ks * 32 + (quad << 3)];

        // ---- S^T = K @ Q^T for both col tiles ----
        f32x4 st[2][4];
        #pragma unroll
        for (int c = 0; c < 2; ++c)
            #pragma unroll
            for (int i = 0; i < 4; ++i) st[c][i] = (f32x4){0.f, 0.f, 0.f, 0.f};
        #pragma unroll
        for (int ks = 0; ks < 2; ++ks)
            #pragma unroll
            for (int mt = 0; mt < 4; ++mt) {
                st[0][mt] = __builtin_amdgcn_mfma_f32_16x16x32_bf16(
                    kf[ks][mt], qf[0][ks], st[0][mt], 0, 0, 0);
                st[1][mt] = __builtin_amdgcn_mfma_f32_16x16x32_bf16(
                    kf[ks][mt], qf[1][ks], st[1][mt], 0, 0, 0);
            }

        // ---- mask + online softmax per col tile (exp2 domain) ----
        const int k0 = kt << 6;
        const bool diag = (kt == last_kt);
        #pragma unroll
        for (int c = 0; c < 2; ++c) {
            float sv[4][4];
            float mloc = -INFINITY;
            if (diag) {
                #pragma unroll
                for (int mt = 0; mt < 4; ++mt) {
                    const int sbase = k0 + mt * 16 + (quad << 2);
                    #pragma unroll
                    for (int r = 0; r < 4; ++r) {
                        float x = st[c][mt][r];
                        if (sbase + r > qg[c]) x = -INFINITY;
                        sv[mt][r] = x;
                        mloc = fmaxf(mloc, x);
                    }
                }
            } else {
                #pragma unroll
                for (int mt = 0; mt < 4; ++mt)
                    #pragma unroll
                    for (int r = 0; r < 4; ++r) {
                        sv[mt][r] = st[c][mt][r];
                        mloc = fmaxf(mloc, st[c][mt][r]);
                    }
            }
            mloc = fmaxf(mloc, __shfl_xor(mloc, 16, 64));
            mloc = fmaxf(mloc, __shfl_xor(mloc, 32, 64));
            const float mnew  = fmaxf(m_i[c], mloc);
            const float alpha = __builtin_amdgcn_exp2f(m_i[c] - mnew);
            float rs = 0.f;
            unsigned short* prow = pw + c * (16 * 72);
            #pragma unroll
            for (int mt = 0; mt < 4; ++mt) {
                const float p0 = __builtin_amdgcn_exp2f(sv[mt][0] - mnew);
                const float p1 = __builtin_amdgcn_exp2f(sv[mt][1] - mnew);
                const float p2 = __builtin_amdgcn_exp2f(sv[mt][2] - mnew);
                const float p3 = __builtin_amdgcn_exp2f(sv[mt][3] - mnew);
                rs += (p0 + p1) + (p2 + p3);
                uint2 pk;
                pk.x = pack_bf16_ru(p0, p1);
                pk.y = pack_bf16_ru(p2, p3);
                *(uint2*)&prow[mt * 16 + (quad << 2)] = pk;
            }
            rs += __shfl_xor(rs, 16, 64);
            rs += __shfl_xor(rs, 32, 64);
            l_i[c] = l_i[c] * alpha + rs;
            m_i[c] = mnew;
            #pragma unroll
            for (int mt = 0; mt < 4; ++mt) {
                oacc[c][mt][0] *= alpha; oacc[c][mt][1] *= alpha;
                oacc[c][mt][2] *= alpha; oacc[c][mt][3] *= alpha;
            }
        }

        // ---- V^T frags (shared), then O^T += V^T @ P^T per col tile ----
        short8 vf[2][4];
        #pragma unroll
        for (int ks = 0; ks < 2; ++ks)
            #pragma unroll
            for (int mt = 0; mt < 4; ++mt)
                vf[ks][mt] = *(const short8*)&Vts[mt * 16 + col][ks * 32 + (quad << 3)];
        #pragma unroll
        for (int c = 0; c < 2; ++c) {
            const unsigned short* prow = pw + c * (16 * 72);
            #pragma unroll
            for (int ks = 0; ks < 2; ++ks) {
                const short8 pf = *(const short8*)&prow[ks * 32 + (quad << 3)];
                #pragma unroll
                for (int mt = 0; mt < 4; ++mt)
                    oacc[c][mt] = __builtin_amdgcn_mfma_f32_16x16x32_bf16(
                        vf[ks][mt], pf, oacc[c][mt], 0, 0, 0);
            }
        }
    }

    // ---- epilogue: normalize, store y[b,t,h,d] (bf16) ----
    #pragma unroll
    for (int c = 0; c < 2; ++c) {
        const float inv = 1.0f / l_i[c];
        unsigned short* yrow = yb + (size_t)(b * T + qg[c]) * 1024 + (h << 6);
        #pragma unroll
        for (int mt = 0; mt < 4; ++mt) {
            ushort4 yv;
            yv.x = f2bf(oacc[c][mt][0] * inv);
            yv.y = f2bf(oacc[c][mt][1] * inv);
            yv.z = f2bf(oacc[c][mt][2] * inv);
            yv.w = f2bf(oacc[c][mt][3] * inv);
            *(ushort4*)&yrow[mt * 16 + (quad << 2)] = yv;
        }
    }
}

// ======================================================================
extern "C" void kernel_launch(void* const* d_in, const int* in_sizes, int n_in,
                              void* d_out, int out_size, void* d_ws, size_t ws_size,
                              hipStream_t stream)
{
    const float* x      = (const float*)d_in[0];
    const float* cosp   = (const float*)d_in[1];
    const float* sinp   = (const float*)d_in[2];
    const float* W_attn = (const float*)d_in[3];
    const float* b_attn = (const float*)d_in[4];
    const float* W_proj = (const float*)d_in[5];
    const float* b_proj = (const float*)d_in[6];
    float* out = (float*)d_out;

    const int C = 1024, H = 16;
    const int T  = in_sizes[1] / 64;     // cos: (T, 64)
    const int BT = in_sizes[0] / C;      // B*T
    const int B  = BT / T;

    unsigned short* qkvb = (unsigned short*)d_ws;              // BT*3072
    unsigned short* xb   = qkvb + (size_t)BT * 3072;           // BT*1024
    unsigned short* Wab  = xb   + (size_t)BT * 1024;           // 3072*1024
    unsigned short* Wpb  = Wab  + (size_t)3072 * 1024;         // 1024*1024
    unsigned short* yb   = Wpb  + (size_t)1024 * 1024;         // BT*1024

    cast_bf16<<<dim3(BT * C / 1024), dim3(256), 0, stream>>>(x, xb, BT * C);
    transpose_cast<<<dim3(3 * C / 32, C / 32), dim3(256), 0, stream>>>(W_attn, Wab, C, 3 * C);
    transpose_cast<<<dim3(C / 32, C / 32), dim3(256), 0, stream>>>(W_proj, Wpb, C, C);

    gemm_bf16<true><<<dim3(3 * C / 128, BT / 128), dim3(256), 0, stream>>>(
        xb, Wab, b_attn, qkvb, BT, 3 * C, C);

    rmsnorm_rope<<<dim3(BT * H * 2 / 4), dim3(256), 0, stream>>>(
        qkvb, cosp, sinp, BT, T);

    flash_attn_mfma<<<dim3(B * H, T / 64), dim3(128), 0, stream>>>(
        qkvb, yb, B, T);

    gemm_bf16<false><<<dim3(C / 128, BT / 128), dim3(256), 0, stream>>>(
        yb, Wpb, b_proj, out, BT, C, C);
}

// Round 8
// 207.304 us; speedup vs baseline: 1.2059x; 1.2059x over previous
//
#include <hip/hip_runtime.h>
#include <math.h>

#define EPSV 1.1920929e-07f

typedef __attribute__((ext_vector_type(8))) short short8;
typedef __attribute__((ext_vector_type(4))) float f32x4;

__device__ __forceinline__ float bf2f(unsigned short u) {
    union { unsigned int i; float f; } c; c.i = ((unsigned int)u) << 16; return c.f;
}
__device__ __forceinline__ unsigned short f2bf(float f) {
    union { float f; unsigned int i; } c; c.f = f;
    unsigned int r = c.i + 0x7FFFu + ((c.i >> 16) & 1u);   // RNE
    return (unsigned short)(r >> 16);
}
// pack two f32 -> two bf16 (round-half-up) in one u32: low=a, high=b
__device__ __forceinline__ unsigned int pack_bf16_ru(float a, float b) {
    union { float f; unsigned int i; } ca, cb; ca.f = a; cb.f = b;
    return __builtin_amdgcn_perm(cb.i + 0x8000u, ca.i + 0x8000u, 0x07060302u);
}
// async global -> LDS, 16 B per lane (dest = wave-uniform base + lane*16)
__device__ __forceinline__ void async_lds16(const unsigned short* g, unsigned short* l) {
    __builtin_amdgcn_global_load_lds(
        (const __attribute__((address_space(1))) unsigned int*)g,
        (__attribute__((address_space(3))) unsigned int*)l, 16, 0, 0);
}

// ======================================================================
// cast fp32 -> bf16 elementwise. 4 elems/thread.
// ======================================================================
__global__ __launch_bounds__(256) void cast_bf16(
    const float* __restrict__ src, unsigned short* __restrict__ dst, int n)
{
    const int i = (blockIdx.x * 256 + threadIdx.x) * 4;
    if (i >= n) return;
    const float4 v = *(const float4*)&src[i];
    ushort4 o;
    o.x = f2bf(v.x); o.y = f2bf(v.y); o.z = f2bf(v.z); o.w = f2bf(v.w);
    *(ushort4*)&dst[i] = o;
}

// ======================================================================
// transpose + cast: W [K][N] fp32 -> Wt [N][K] bf16. 32x32 tiles.
// ======================================================================
__global__ __launch_bounds__(256) void transpose_cast(
    const float* __restrict__ W, unsigned short* __restrict__ Wt, int K, int N)
{
    __shared__ float tile[32][33];
    const int n0 = blockIdx.x * 32, k0 = blockIdx.y * 32;
    const int r = threadIdx.x >> 3, c4 = (threadIdx.x & 7) * 4;
    const float4 v = *(const float4*)&W[(size_t)(k0 + r) * N + n0 + c4];
    tile[r][c4 + 0] = v.x; tile[r][c4 + 1] = v.y;
    tile[r][c4 + 2] = v.z; tile[r][c4 + 3] = v.w;
    __syncthreads();
    ushort4 o;
    o.x = f2bf(tile[c4 + 0][r]); o.y = f2bf(tile[c4 + 1][r]);
    o.z = f2bf(tile[c4 + 2][r]); o.w = f2bf(tile[c4 + 3][r]);
    *(ushort4*)&Wt[(size_t)(n0 + r) * K + k0 + c4] = o;
}

// ======================================================================
// bf16 MFMA GEMM, m97 structure: C[M,N] = A[M,K] @ Bt[N,K]^T + bias[N]
// 128x128x32 tile; global_load_lds width-16 staging into unpadded
// [128][32] LDS (dest = wave base + lane*16, matched layout).
// ======================================================================
template <bool OUT_BF16>
__global__ __launch_bounds__(256) void gemm_bf16(
    const unsigned short* __restrict__ A,
    const unsigned short* __restrict__ Bt,
    const float* __restrict__ bias,
    void* __restrict__ Cv,
    int M, int N, int K)
{
    __shared__ unsigned short As[128][32];
    __shared__ unsigned short Bs[128][32];
    const int t    = threadIdx.x;
    const int lane = t & 63;
    const int wv   = t >> 6;
    const int wrow = (wv >> 1) * 64;
    const int wcol = (wv & 1) * 64;
    const int m0 = blockIdx.y * 128;
    const int n0 = blockIdx.x * 128;
    const int col  = lane & 15;
    const int quad = lane >> 4;

    const int srow = (wv << 5) + (lane >> 2);     // wv*32 + 0..15
    const int scol = (lane & 3) << 3;             // 0,8,16,24
    const unsigned short* ap0 = A  + (size_t)(m0 + srow) * K + scol;
    const unsigned short* ap1 = ap0 + (size_t)16 * K;
    const unsigned short* bp0 = Bt + (size_t)(n0 + srow) * K + scol;
    const unsigned short* bp1 = bp0 + (size_t)16 * K;
    unsigned short* al0 = &As[srow][scol];
    unsigned short* al1 = &As[srow + 16][scol];
    unsigned short* bl0 = &Bs[srow][scol];
    unsigned short* bl1 = &Bs[srow + 16][scol];

    f32x4 acc[4][4];
    #pragma unroll
    for (int i = 0; i < 4; ++i)
        #pragma unroll
        for (int j = 0; j < 4; ++j)
            acc[i][j] = (f32x4){0.f, 0.f, 0.f, 0.f};

    for (int k0 = 0; k0 < K; k0 += 32) {
        async_lds16(ap0, al0);
        async_lds16(ap1, al1);
        async_lds16(bp0, bl0);
        async_lds16(bp1, bl1);
        ap0 += 32; ap1 += 32; bp0 += 32; bp1 += 32;
        __syncthreads();
        short8 af[4], bf[4];
        #pragma unroll
        for (int mt = 0; mt < 4; ++mt)
            af[mt] = *(const short8*)&As[wrow + mt * 16 + col][quad << 3];
        #pragma unroll
        for (int nt = 0; nt < 4; ++nt)
            bf[nt] = *(const short8*)&Bs[wcol + nt * 16 + col][quad << 3];
        #pragma unroll
        for (int mt = 0; mt < 4; ++mt)
            #pragma unroll
            for (int nt = 0; nt < 4; ++nt)
                acc[mt][nt] = __builtin_amdgcn_mfma_f32_16x16x32_bf16(
                    af[mt], bf[nt], acc[mt][nt], 0, 0, 0);
        __syncthreads();
    }

    const int rowq = quad << 2;
    #pragma unroll
    for (int nt = 0; nt < 4; ++nt) {
        const int n = n0 + wcol + nt * 16 + col;
        const float bv = bias[n];
        #pragma unroll
        for (int mt = 0; mt < 4; ++mt) {
            #pragma unroll
            for (int r = 0; r < 4; ++r) {
                const int m = m0 + wrow + mt * 16 + rowq + r;
                const float v = acc[mt][nt][r] + bv;
                if (OUT_BF16)
                    ((unsigned short*)Cv)[(size_t)m * N + n] = f2bf(v);
                else
                    ((float*)Cv)[(size_t)m * N + n] = v;
            }
        }
    }
}

// ======================================================================
// bf16 MFMA GEMM, 128(M) x 64(N) tile variant (for skinny-N gemm2:
// doubles grid occupancy vs 128x128). 4 waves stacked in M; each wave
// 32 rows x 64 cols = 2x4 MFMA tiles. fp32 out.
// ======================================================================
__global__ __launch_bounds__(256) void gemm_bf16_n64(
    const unsigned short* __restrict__ A,
    const unsigned short* __restrict__ Bt,
    const float* __restrict__ bias,
    float* __restrict__ C,
    int M, int N, int K)
{
    __shared__ unsigned short As[128][32];
    __shared__ unsigned short Bs[64][32];
    const int t    = threadIdx.x;
    const int lane = t & 63;
    const int wv   = t >> 6;
    const int wrow = wv << 5;                     // wave rows: wv*32..+31
    const int m0 = blockIdx.y * 128;
    const int n0 = blockIdx.x * 64;
    const int col  = lane & 15;
    const int quad = lane >> 4;

    const int srow = (wv << 5) + (lane >> 2);     // A: wv*32 + 0..15
    const int scol = (lane & 3) << 3;
    const unsigned short* ap0 = A  + (size_t)(m0 + srow) * K + scol;
    const unsigned short* ap1 = ap0 + (size_t)16 * K;
    const int bsrow = (wv << 4) + (lane >> 2);    // B: wv*16 + 0..15
    const unsigned short* bp0 = Bt + (size_t)(n0 + bsrow) * K + scol;
    unsigned short* al0 = &As[srow][scol];
    unsigned short* al1 = &As[srow + 16][scol];
    unsigned short* bl0 = &Bs[bsrow][scol];

    f32x4 acc[2][4];
    #pragma unroll
    for (int i = 0; i < 2; ++i)
        #pragma unroll
        for (int j = 0; j < 4; ++j)
            acc[i][j] = (f32x4){0.f, 0.f, 0.f, 0.f};

    for (int k0 = 0; k0 < K; k0 += 32) {
        async_lds16(ap0, al0);
        async_lds16(ap1, al1);
        async_lds16(bp0, bl0);
        ap0 += 32; ap1 += 32; bp0 += 32;
        __syncthreads();
        short8 af[2], bf[4];
        #pragma unroll
        for (int mt = 0; mt < 2; ++mt)
            af[mt] = *(const short8*)&As[wrow + mt * 16 + col][quad << 3];
        #pragma unroll
        for (int nt = 0; nt < 4; ++nt)
            bf[nt] = *(const short8*)&Bs[nt * 16 + col][quad << 3];
        #pragma unroll
        for (int mt = 0; mt < 2; ++mt)
            #pragma unroll
            for (int nt = 0; nt < 4; ++nt)
                acc[mt][nt] = __builtin_amdgcn_mfma_f32_16x16x32_bf16(
                    af[mt], bf[nt], acc[mt][nt], 0, 0, 0);
        __syncthreads();
    }

    const int rowq = quad << 2;
    #pragma unroll
    for (int nt = 0; nt < 4; ++nt) {
        const int n = n0 + nt * 16 + col;
        const float bv = bias[n];
        #pragma unroll
        for (int mt = 0; mt < 2; ++mt) {
            #pragma unroll
            for (int r = 0; r < 4; ++r) {
                const int m = m0 + wrow + mt * 16 + rowq + r;
                C[(size_t)m * N + n] = acc[mt][nt][r] + bv;
            }
        }
    }
}

// ======================================================================
// RMSNorm (D=64) then rotary, in-place on bf16 q/k slices.
// 4 rows per wave: 16 lanes per row, ushort4/float4 vector loads.
// q output pre-scaled by log2e/8 (folds softmax scale -> exp2 domain).
// ======================================================================
__global__ __launch_bounds__(256) void rmsnorm_rope(
    unsigned short* __restrict__ qkv, const float* __restrict__ cosp,
    const float* __restrict__ sinp, int BT, int T)
{
    const int wid  = (blockIdx.x << 2) + (threadIdx.x >> 6);
    const int lane = threadIdx.x & 63;
    const int hq = wid & 3;              // head group of 4
    const int w  = (wid >> 2) & 1;       // 0 = q, 1 = k
    const int bt = wid >> 3;
    if (bt >= BT) return;
    const int h  = (hq << 2) + (lane >> 4);
    const int d4 = (lane & 15) << 2;
    const int tpos = bt % T;
    const size_t idx = (size_t)bt * 3072 + (w << 10) + (h << 6) + d4;

    const ushort4 u = *(const ushort4*)&qkv[idx];
    const float x0 = bf2f(u.x), x1 = bf2f(u.y), x2 = bf2f(u.z), x3 = bf2f(u.w);
    float ss = x0 * x0 + x1 * x1 + x2 * x2 + x3 * x3;
    ss += __shfl_xor(ss, 1, 64);
    ss += __shfl_xor(ss, 2, 64);
    ss += __shfl_xor(ss, 4, 64);
    ss += __shfl_xor(ss, 8, 64);
    const float rn = rsqrtf(ss * (1.0f / 64.0f) + EPSV);
    const float xn0 = x0 * rn, xn1 = x1 * rn, xn2 = x2 * rn, xn3 = x3 * rn;
    // rotary partner chunk: lane ^ 8 within the 16-lane row group (d ^ 32)
    const float p0 = __shfl_xor(xn0, 8, 64);
    const float p1 = __shfl_xor(xn1, 8, 64);
    const float p2 = __shfl_xor(xn2, 8, 64);
    const float p3 = __shfl_xor(xn3, 8, 64);
    const float sgn = (d4 < 32) ? -1.0f : 1.0f;
    const float4 c = *(const float4*)&cosp[tpos * 64 + d4];
    const float4 s = *(const float4*)&sinp[tpos * 64 + d4];
    const float scale = (w == 0) ? 0.18033688011112042f : 1.0f;  // log2e/8
    ushort4 o;
    o.x = f2bf(fmaf(xn0, c.x, sgn * p0 * s.x) * scale);
    o.y = f2bf(fmaf(xn1, c.y, sgn * p1 * s.y) * scale);
    o.z = f2bf(fmaf(xn2, c.z, sgn * p2 * s.z) * scale);
    o.w = f2bf(fmaf(xn3, c.w, sgn * p3 * s.w) * scale);
    *(ushort4*)&qkv[idx] = o;
}

// ======================================================================
// V transpose: qkv v-slice [b,t,h,d] -> vt [b,h,d,t]. 64x64 tiles.
// ======================================================================
__global__ __launch_bounds__(256) void v_transpose(
    const unsigned short* __restrict__ qkv, unsigned short* __restrict__ vt,
    int T)
{
    __shared__ unsigned short tile[64][72];
    const int bh = blockIdx.x;
    const int b  = bh >> 4, h = bh & 15;
    const int t0 = blockIdx.y << 6;
    const int t  = threadIdx.x;
    const unsigned short* vbase = qkv + (size_t)b * T * 3072 + 2048 + (h << 6);

    #pragma unroll
    for (int i = 0; i < 2; ++i) {
        const int c = t + (i << 8);
        const int r = c >> 3, c8 = (c & 7) << 3;
        const short8 v = *(const short8*)&vbase[(size_t)(t0 + r) * 3072 + c8];
        #pragma unroll
        for (int j = 0; j < 8; ++j)
            tile[c8 + j][r] = (unsigned short)v[j];
    }
    __syncthreads();
    #pragma unroll
    for (int i = 0; i < 2; ++i) {
        const int c = t + (i << 8);
        const int d = c >> 3, c8 = (c & 7) << 3;
        const short8 o = *(const short8*)&tile[d][c8];
        *(short8*)&vt[((size_t)bh * 64 + d) * T + t0 + c8] = o;
    }
}

// ======================================================================
// MFMA flash attention (r6 structure, measured 51 us). Block = (b,h) x
// 64 q-rows, 4 waves; K/V^T staged in LDS per 64-s tile (2 barriers/kt).
// S^T = K Q^T (per-lane softmax state, col = q); PV as O^T = V^T P^T.
// exp2-domain softmax (q pre-scaled by log2e/8 in rmsnorm_rope).
// ======================================================================
__global__ __launch_bounds__(256) void flash_attn_mfma(
    const unsigned short* __restrict__ qkv,
    const unsigned short* __restrict__ vt,
    unsigned short* __restrict__ yb,
    int B, int T)
{
    const int bh = blockIdx.x;
    const int b  = bh >> 4, h = bh & 15;
    const int q0 = ((int)gridDim.y - 1 - (int)blockIdx.y) << 6;  // heavy first
    const int t  = threadIdx.x;
    const int lane = t & 63;
    const int w    = t >> 6;
    const int col  = lane & 15;
    const int quad = lane >> 4;

    __shared__ unsigned short Ks [64][72];
    __shared__ unsigned short Vts[64][72];
    __shared__ unsigned short Ps [4][16][72];   // per-wave [q-col][s]

    const unsigned short* qb  = qkv + (size_t)b * T * 3072 + (h << 6);
    const unsigned short* kb  = qb + 1024;
    const unsigned short* vtb = vt + (size_t)bh * 64 * T;

    const int qw = q0 + w * 16;        // wave's first q row
    const int qg = qw + col;           // lane's q row

    // ---- Q B-frags: direct b128 loads (pre-scaled by log2e/8) ----
    short8 qf[2];
    {
        const unsigned short* qrow = qb + (size_t)qg * 3072 + (quad << 3);
        qf[0] = *(const short8*)&qrow[0];
        qf[1] = *(const short8*)&qrow[32];
    }

    f32x4 oacc[4];
    #pragma unroll
    for (int i = 0; i < 4; ++i) oacc[i] = (f32x4){0.f, 0.f, 0.f, 0.f};
    float m_i = -INFINITY, l_i = 0.f;

    // ---- hoisted staging pointers (+const increments per kt) ----
    const int sr = t >> 3, sc = (t & 7) << 3;   // 32 rows x 64 cols per pass
    const unsigned short* kp0 = kb  + (size_t)sr * 3072 + sc;
    const unsigned short* kp1 = kp0 + (size_t)32 * 3072;
    const unsigned short* vp0 = vtb + (size_t)sr * T + sc;
    const unsigned short* vp1 = vp0 + (size_t)32 * T;
    unsigned short* kw0 = &Ks[sr][sc];
    unsigned short* kw1 = &Ks[sr + 32][sc];
    unsigned short* vw0 = &Vts[sr][sc];
    unsigned short* vw1 = &Vts[sr + 32][sc];
    unsigned short* pw  = &Ps[w][col][0];

    const int last_kt = q0 >> 6;
    for (int kt = 0; kt <= last_kt; ++kt) {
        const int k0 = kt << 6;
        __syncthreads();   // prev compute done reading LDS
        *(short8*)kw0 = *(const short8*)kp0;
        *(short8*)kw1 = *(const short8*)kp1;
        *(short8*)vw0 = *(const short8*)vp0;
        *(short8*)vw1 = *(const short8*)vp1;
        kp0 += 64 * 3072; kp1 += 64 * 3072; vp0 += 64; vp1 += 64;
        __syncthreads();

        // ---- S^T = K @ Q^T ----
        f32x4 st[4];
        #pragma unroll
        for (int i = 0; i < 4; ++i) st[i] = (f32x4){0.f, 0.f, 0.f, 0.f};
        #pragma unroll
        for (int ks = 0; ks < 2; ++ks)
            #pragma unroll
            for (int mt = 0; mt < 4; ++mt) {
                const short8 kf = *(const short8*)&Ks[mt * 16 + col][ks * 32 + (quad << 3)];
                st[mt] = __builtin_amdgcn_mfma_f32_16x16x32_bf16(kf, qf[ks], st[mt], 0, 0, 0);
            }

        // ---- mask + online softmax (exp2 domain; per-lane, col = q) ----
        float sv[4][4];
        float mloc = -INFINITY;
        if (k0 + 63 > qw) {                       // diagonal tile
            #pragma unroll
            for (int mt = 0; mt < 4; ++mt) {
                const int sbase = k0 + mt * 16 + (quad << 2);
                #pragma unroll
                for (int r = 0; r < 4; ++r) {
                    float x = st[mt][r];
                    if (sbase + r > qg) x = -INFINITY;
                    sv[mt][r] = x;
                    mloc = fmaxf(mloc, x);
                }
            }
        } else {
            #pragma unroll
            for (int mt = 0; mt < 4; ++mt)
                #pragma unroll
                for (int r = 0; r < 4; ++r) {
                    sv[mt][r] = st[mt][r];
                    mloc = fmaxf(mloc, st[mt][r]);
                }
        }
        mloc = fmaxf(mloc, __shfl_xor(mloc, 16, 64));
        mloc = fmaxf(mloc, __shfl_xor(mloc, 32, 64));
        const float mnew  = fmaxf(m_i, mloc);
        const float alpha = __builtin_amdgcn_exp2f(m_i - mnew);
        float rs = 0.f;
        #pragma unroll
        for (int mt = 0; mt < 4; ++mt) {
            const float p0 = __builtin_amdgcn_exp2f(sv[mt][0] - mnew);
            const float p1 = __builtin_amdgcn_exp2f(sv[mt][1] - mnew);
            const float p2 = __builtin_amdgcn_exp2f(sv[mt][2] - mnew);
            const float p3 = __builtin_amdgcn_exp2f(sv[mt][3] - mnew);
            rs += (p0 + p1) + (p2 + p3);
            uint2 pk;
            pk.x = pack_bf16_ru(p0, p1);
            pk.y = pack_bf16_ru(p2, p3);
            *(uint2*)&pw[mt * 16 + (quad << 2)] = pk;
        }
        rs += __shfl_xor(rs, 16, 64);
        rs += __shfl_xor(rs, 32, 64);
        l_i = l_i * alpha + rs;
        m_i = mnew;
        #pragma unroll
        for (int mt = 0; mt < 4; ++mt) {
            oacc[mt][0] *= alpha; oacc[mt][1] *= alpha;
            oacc[mt][2] *= alpha; oacc[mt][3] *= alpha;
        }

        // ---- O^T += V^T @ P^T ----
        #pragma unroll
        for (int ks = 0; ks < 2; ++ks) {
            const short8 pf = *(const short8*)&pw[ks * 32 + (quad << 3)];
            #pragma unroll
            for (int mt = 0; mt < 4; ++mt) {
                const short8 vf = *(const short8*)&Vts[mt * 16 + col][ks * 32 + (quad << 3)];
                oacc[mt] = __builtin_amdgcn_mfma_f32_16x16x32_bf16(vf, pf, oacc[mt], 0, 0, 0);
            }
        }
    }

    // ---- epilogue: normalize, store y[b,t,h,d] (bf16) ----
    const float inv = 1.0f / l_i;
    unsigned short* yrow = yb + (size_t)(b * T + qg) * 1024 + (h << 6);
    #pragma unroll
    for (int mt = 0; mt < 4; ++mt) {
        ushort4 yv;
        yv.x = f2bf(oacc[mt][0] * inv);
        yv.y = f2bf(oacc[mt][1] * inv);
        yv.z = f2bf(oacc[mt][2] * inv);
        yv.w = f2bf(oacc[mt][3] * inv);
        *(ushort4*)&yrow[mt * 16 + (quad << 2)] = yv;
    }
}

// ======================================================================
extern "C" void kernel_launch(void* const* d_in, const int* in_sizes, int n_in,
                              void* d_out, int out_size, void* d_ws, size_t ws_size,
                              hipStream_t stream)
{
    const float* x      = (const float*)d_in[0];
    const float* cosp   = (const float*)d_in[1];
    const float* sinp   = (const float*)d_in[2];
    const float* W_attn = (const float*)d_in[3];
    const float* b_attn = (const float*)d_in[4];
    const float* W_proj = (const float*)d_in[5];
    const float* b_proj = (const float*)d_in[6];
    float* out = (float*)d_out;

    const int C = 1024, H = 16;
    const int T  = in_sizes[1] / 64;     // cos: (T, 64)
    const int BT = in_sizes[0] / C;      // B*T
    const int B  = BT / T;

    unsigned short* qkvb = (unsigned short*)d_ws;              // BT*3072
    unsigned short* xb   = qkvb + (size_t)BT * 3072;           // BT*1024
    unsigned short* Wab  = xb   + (size_t)BT * 1024;           // 3072*1024
    unsigned short* Wpb  = Wab  + (size_t)3072 * 1024;         // 1024*1024
    unsigned short* yb   = Wpb  + (size_t)1024 * 1024;         // BT*1024
    unsigned short* vtb  = xb;   // vt aliases xb (x dead after gemm1)

    cast_bf16<<<dim3(BT * C / 1024), dim3(256), 0, stream>>>(x, xb, BT * C);
    transpose_cast<<<dim3(3 * C / 32, C / 32), dim3(256), 0, stream>>>(W_attn, Wab, C, 3 * C);
    transpose_cast<<<dim3(C / 32, C / 32), dim3(256), 0, stream>>>(W_proj, Wpb, C, C);

    gemm_bf16<true><<<dim3(3 * C / 128, BT / 128), dim3(256), 0, stream>>>(
        xb, Wab, b_attn, qkvb, BT, 3 * C, C);

    rmsnorm_rope<<<dim3(BT * 2), dim3(256), 0, stream>>>(
        qkvb, cosp, sinp, BT, T);

    v_transpose<<<dim3(B * H, T / 64), dim3(256), 0, stream>>>(qkvb, vtb, T);

    flash_attn_mfma<<<dim3(B * H, T / 64), dim3(256), 0, stream>>>(
        qkvb, vtb, yb, B, T);

    gemm_bf16_n64<<<dim3(C / 64, BT / 128), dim3(256), 0, stream>>>(
        yb, Wpb, b_proj, out, BT, C, C);
}

// Round 9
// 202.464 us; speedup vs baseline: 1.2347x; 1.0239x over previous
//
#include <hip/hip_runtime.h>
#include <math.h>

#define EPSV 1.1920929e-07f

typedef __attribute__((ext_vector_type(8))) short short8;
typedef __attribute__((ext_vector_type(4))) float f32x4;

__device__ __forceinline__ float bf2f(unsigned short u) {
    union { unsigned int i; float f; } c; c.i = ((unsigned int)u) << 16; return c.f;
}
__device__ __forceinline__ unsigned short f2bf(float f) {
    union { float f; unsigned int i; } c; c.f = f;
    unsigned int r = c.i + 0x7FFFu + ((c.i >> 16) & 1u);   // RNE
    return (unsigned short)(r >> 16);
}
// pack two f32 -> two bf16 (round-half-up) in one u32: low=a, high=b
__device__ __forceinline__ unsigned int pack_bf16_ru(float a, float b) {
    union { float f; unsigned int i; } ca, cb; ca.f = a; cb.f = b;
    return __builtin_amdgcn_perm(cb.i + 0x8000u, ca.i + 0x8000u, 0x07060302u);
}
// async global -> LDS, 16 B per lane (dest = wave-uniform base + lane*16)
__device__ __forceinline__ void async_lds16(const unsigned short* g, unsigned short* l) {
    __builtin_amdgcn_global_load_lds(
        (const __attribute__((address_space(1))) unsigned int*)g,
        (__attribute__((address_space(3))) unsigned int*)l, 16, 0, 0);
}

// ======================================================================
// cast fp32 -> bf16 elementwise. 4 elems/thread.
// ======================================================================
__global__ __launch_bounds__(256) void cast_bf16(
    const float* __restrict__ src, unsigned short* __restrict__ dst, int n)
{
    const int i = (blockIdx.x * 256 + threadIdx.x) * 4;
    if (i >= n) return;
    const float4 v = *(const float4*)&src[i];
    ushort4 o;
    o.x = f2bf(v.x); o.y = f2bf(v.y); o.z = f2bf(v.z); o.w = f2bf(v.w);
    *(ushort4*)&dst[i] = o;
}

// ======================================================================
// transpose + cast for BOTH weights in one launch (fewer dispatches):
// W_attn [1024][3072] -> Wat [3072][1024]; W_proj [1024][1024] -> Wpt.
// 32x32 tiles; K = 1024 rows for both.
// ======================================================================
__global__ __launch_bounds__(256) void transpose_cast_both(
    const float* __restrict__ Wa, unsigned short* __restrict__ Wat,
    const float* __restrict__ Wp, unsigned short* __restrict__ Wpt)
{
    __shared__ float tile[32][33];
    int bx = blockIdx.x;
    const float* W; unsigned short* Wt; int N;
    if (bx < 96) { W = Wa; Wt = Wat; N = 3072; }
    else         { W = Wp; Wt = Wpt; N = 1024; bx -= 96; }
    const int n0 = bx * 32, k0 = blockIdx.y * 32;
    const int r = threadIdx.x >> 3, c4 = (threadIdx.x & 7) * 4;
    const float4 v = *(const float4*)&W[(size_t)(k0 + r) * N + n0 + c4];
    tile[r][c4 + 0] = v.x; tile[r][c4 + 1] = v.y;
    tile[r][c4 + 2] = v.z; tile[r][c4 + 3] = v.w;
    __syncthreads();
    ushort4 o;
    o.x = f2bf(tile[c4 + 0][r]); o.y = f2bf(tile[c4 + 1][r]);
    o.z = f2bf(tile[c4 + 2][r]); o.w = f2bf(tile[c4 + 3][r]);
    *(ushort4*)&Wt[(size_t)(n0 + r) * 1024 + k0 + c4] = o;
}

// ======================================================================
// bf16 MFMA GEMM, m97 structure: C[M,N] = A[M,K] @ Bt[N,K]^T + bias[N]
// 128x128x32 tile; global_load_lds width-16 staging into unpadded
// [128][32] LDS (dest = wave base + lane*16, matched layout).
// ======================================================================
template <bool OUT_BF16>
__global__ __launch_bounds__(256) void gemm_bf16(
    const unsigned short* __restrict__ A,
    const unsigned short* __restrict__ Bt,
    const float* __restrict__ bias,
    void* __restrict__ Cv,
    int M, int N, int K)
{
    __shared__ unsigned short As[128][32];
    __shared__ unsigned short Bs[128][32];
    const int t    = threadIdx.x;
    const int lane = t & 63;
    const int wv   = t >> 6;
    const int wrow = (wv >> 1) * 64;
    const int wcol = (wv & 1) * 64;
    const int m0 = blockIdx.y * 128;
    const int n0 = blockIdx.x * 128;
    const int col  = lane & 15;
    const int quad = lane >> 4;

    const int srow = (wv << 5) + (lane >> 2);     // wv*32 + 0..15
    const int scol = (lane & 3) << 3;             // 0,8,16,24
    const unsigned short* ap0 = A  + (size_t)(m0 + srow) * K + scol;
    const unsigned short* ap1 = ap0 + (size_t)16 * K;
    const unsigned short* bp0 = Bt + (size_t)(n0 + srow) * K + scol;
    const unsigned short* bp1 = bp0 + (size_t)16 * K;
    unsigned short* al0 = &As[srow][scol];
    unsigned short* al1 = &As[srow + 16][scol];
    unsigned short* bl0 = &Bs[srow][scol];
    unsigned short* bl1 = &Bs[srow + 16][scol];

    f32x4 acc[4][4];
    #pragma unroll
    for (int i = 0; i < 4; ++i)
        #pragma unroll
        for (int j = 0; j < 4; ++j)
            acc[i][j] = (f32x4){0.f, 0.f, 0.f, 0.f};

    for (int k0 = 0; k0 < K; k0 += 32) {
        async_lds16(ap0, al0);
        async_lds16(ap1, al1);
        async_lds16(bp0, bl0);
        async_lds16(bp1, bl1);
        ap0 += 32; ap1 += 32; bp0 += 32; bp1 += 32;
        __syncthreads();
        short8 af[4], bf[4];
        #pragma unroll
        for (int mt = 0; mt < 4; ++mt)
            af[mt] = *(const short8*)&As[wrow + mt * 16 + col][quad << 3];
        #pragma unroll
        for (int nt = 0; nt < 4; ++nt)
            bf[nt] = *(const short8*)&Bs[wcol + nt * 16 + col][quad << 3];
        #pragma unroll
        for (int mt = 0; mt < 4; ++mt)
            #pragma unroll
            for (int nt = 0; nt < 4; ++nt)
                acc[mt][nt] = __builtin_amdgcn_mfma_f32_16x16x32_bf16(
                    af[mt], bf[nt], acc[mt][nt], 0, 0, 0);
        __syncthreads();
    }

    const int rowq = quad << 2;
    #pragma unroll
    for (int nt = 0; nt < 4; ++nt) {
        const int n = n0 + wcol + nt * 16 + col;
        const float bv = bias[n];
        #pragma unroll
        for (int mt = 0; mt < 4; ++mt) {
            #pragma unroll
            for (int r = 0; r < 4; ++r) {
                const int m = m0 + wrow + mt * 16 + rowq + r;
                const float v = acc[mt][nt][r] + bv;
                if (OUT_BF16)
                    ((unsigned short*)Cv)[(size_t)m * N + n] = f2bf(v);
                else
                    ((float*)Cv)[(size_t)m * N + n] = v;
            }
        }
    }
}

// ======================================================================
// bf16 MFMA GEMM, 128(M) x 64(N) tile variant (skinny-N gemm2). fp32 out.
// ======================================================================
__global__ __launch_bounds__(256) void gemm_bf16_n64(
    const unsigned short* __restrict__ A,
    const unsigned short* __restrict__ Bt,
    const float* __restrict__ bias,
    float* __restrict__ C,
    int M, int N, int K)
{
    __shared__ unsigned short As[128][32];
    __shared__ unsigned short Bs[64][32];
    const int t    = threadIdx.x;
    const int lane = t & 63;
    const int wv   = t >> 6;
    const int wrow = wv << 5;
    const int m0 = blockIdx.y * 128;
    const int n0 = blockIdx.x * 64;
    const int col  = lane & 15;
    const int quad = lane >> 4;

    const int srow = (wv << 5) + (lane >> 2);
    const int scol = (lane & 3) << 3;
    const unsigned short* ap0 = A  + (size_t)(m0 + srow) * K + scol;
    const unsigned short* ap1 = ap0 + (size_t)16 * K;
    const int bsrow = (wv << 4) + (lane >> 2);
    const unsigned short* bp0 = Bt + (size_t)(n0 + bsrow) * K + scol;
    unsigned short* al0 = &As[srow][scol];
    unsigned short* al1 = &As[srow + 16][scol];
    unsigned short* bl0 = &Bs[bsrow][scol];

    f32x4 acc[2][4];
    #pragma unroll
    for (int i = 0; i < 2; ++i)
        #pragma unroll
        for (int j = 0; j < 4; ++j)
            acc[i][j] = (f32x4){0.f, 0.f, 0.f, 0.f};

    for (int k0 = 0; k0 < K; k0 += 32) {
        async_lds16(ap0, al0);
        async_lds16(ap1, al1);
        async_lds16(bp0, bl0);
        ap0 += 32; ap1 += 32; bp0 += 32;
        __syncthreads();
        short8 af[2], bf[4];
        #pragma unroll
        for (int mt = 0; mt < 2; ++mt)
            af[mt] = *(const short8*)&As[wrow + mt * 16 + col][quad << 3];
        #pragma unroll
        for (int nt = 0; nt < 4; ++nt)
            bf[nt] = *(const short8*)&Bs[nt * 16 + col][quad << 3];
        #pragma unroll
        for (int mt = 0; mt < 2; ++mt)
            #pragma unroll
            for (int nt = 0; nt < 4; ++nt)
                acc[mt][nt] = __builtin_amdgcn_mfma_f32_16x16x32_bf16(
                    af[mt], bf[nt], acc[mt][nt], 0, 0, 0);
        __syncthreads();
    }

    const int rowq = quad << 2;
    #pragma unroll
    for (int nt = 0; nt < 4; ++nt) {
        const int n = n0 + nt * 16 + col;
        const float bv = bias[n];
        #pragma unroll
        for (int mt = 0; mt < 2; ++mt) {
            #pragma unroll
            for (int r = 0; r < 4; ++r) {
                const int m = m0 + wrow + mt * 16 + rowq + r;
                C[(size_t)m * N + n] = acc[mt][nt][r] + bv;
            }
        }
    }
}

// ======================================================================
// RMSNorm (D=64) then rotary, in-place on bf16 q/k slices.
// 4 rows per wave: 16 lanes per row, ushort4/float4 vector loads.
// q output pre-scaled by log2e/8 (folds softmax scale -> exp2 domain).
// ======================================================================
__global__ __launch_bounds__(256) void rmsnorm_rope(
    unsigned short* __restrict__ qkv, const float* __restrict__ cosp,
    const float* __restrict__ sinp, int BT, int T)
{
    const int wid  = (blockIdx.x << 2) + (threadIdx.x >> 6);
    const int lane = threadIdx.x & 63;
    const int hq = wid & 3;
    const int w  = (wid >> 2) & 1;
    const int bt = wid >> 3;
    if (bt >= BT) return;
    const int h  = (hq << 2) + (lane >> 4);
    const int d4 = (lane & 15) << 2;
    const int tpos = bt % T;
    const size_t idx = (size_t)bt * 3072 + (w << 10) + (h << 6) + d4;

    const ushort4 u = *(const ushort4*)&qkv[idx];
    const float x0 = bf2f(u.x), x1 = bf2f(u.y), x2 = bf2f(u.z), x3 = bf2f(u.w);
    float ss = x0 * x0 + x1 * x1 + x2 * x2 + x3 * x3;
    ss += __shfl_xor(ss, 1, 64);
    ss += __shfl_xor(ss, 2, 64);
    ss += __shfl_xor(ss, 4, 64);
    ss += __shfl_xor(ss, 8, 64);
    const float rn = rsqrtf(ss * (1.0f / 64.0f) + EPSV);
    const float xn0 = x0 * rn, xn1 = x1 * rn, xn2 = x2 * rn, xn3 = x3 * rn;
    const float p0 = __shfl_xor(xn0, 8, 64);
    const float p1 = __shfl_xor(xn1, 8, 64);
    const float p2 = __shfl_xor(xn2, 8, 64);
    const float p3 = __shfl_xor(xn3, 8, 64);
    const float sgn = (d4 < 32) ? -1.0f : 1.0f;
    const float4 c = *(const float4*)&cosp[tpos * 64 + d4];
    const float4 s = *(const float4*)&sinp[tpos * 64 + d4];
    const float scale = (w == 0) ? 0.18033688011112042f : 1.0f;  // log2e/8
    ushort4 o;
    o.x = f2bf(fmaf(xn0, c.x, sgn * p0 * s.x) * scale);
    o.y = f2bf(fmaf(xn1, c.y, sgn * p1 * s.y) * scale);
    o.z = f2bf(fmaf(xn2, c.z, sgn * p2 * s.z) * scale);
    o.w = f2bf(fmaf(xn3, c.w, sgn * p3 * s.w) * scale);
    *(ushort4*)&qkv[idx] = o;
}

// ======================================================================
// V transpose: qkv v-slice [b,t,h,d] -> vt [b,h,d,t]. 64x64 tiles.
// ======================================================================
__global__ __launch_bounds__(256) void v_transpose(
    const unsigned short* __restrict__ qkv, unsigned short* __restrict__ vt,
    int T)
{
    __shared__ unsigned short tile[64][72];
    const int bh = blockIdx.x;
    const int b  = bh >> 4, h = bh & 15;
    const int t0 = blockIdx.y << 6;
    const int t  = threadIdx.x;
    const unsigned short* vbase = qkv + (size_t)b * T * 3072 + 2048 + (h << 6);

    #pragma unroll
    for (int i = 0; i < 2; ++i) {
        const int c = t + (i << 8);
        const int r = c >> 3, c8 = (c & 7) << 3;
        const short8 v = *(const short8*)&vbase[(size_t)(t0 + r) * 3072 + c8];
        #pragma unroll
        for (int j = 0; j < 8; ++j)
            tile[c8 + j][r] = (unsigned short)v[j];
    }
    __syncthreads();
    #pragma unroll
    for (int i = 0; i < 2; ++i) {
        const int c = t + (i << 8);
        const int d = c >> 3, c8 = (c & 7) << 3;
        const short8 o = *(const short8*)&tile[d][c8];
        *(short8*)&vt[((size_t)bh * 64 + d) * T + t0 + c8] = o;
    }
}

// ======================================================================
// MFMA flash attention, FIXED-MAX softmax (no online rescaling):
// rms_norm bounds |q^.k^| <= 64, so s*log2e/8 <= 11.6 and p = exp2(s)
// can never overflow fp32 -- no running max, no alpha, no max shuffles.
// Block = (b,h) x 64 q-rows, 4 waves; K/V^T staged in LDS; next tile
// register-prefetched after the 2nd barrier (overlaps compute).
// S^T = K Q^T (per-lane state, col = q); PV as O^T = V^T P^T.
// ======================================================================
__global__ __launch_bounds__(256) void flash_attn_mfma(
    const unsigned short* __restrict__ qkv,
    const unsigned short* __restrict__ vt,
    unsigned short* __restrict__ yb,
    int B, int T)
{
    const int bh = blockIdx.x;
    const int b  = bh >> 4, h = bh & 15;
    const int q0 = ((int)gridDim.y - 1 - (int)blockIdx.y) << 6;  // heavy first
    const int t  = threadIdx.x;
    const int lane = t & 63;
    const int w    = t >> 6;
    const int col  = lane & 15;
    const int quad = lane >> 4;

    __shared__ unsigned short Ks [64][72];
    __shared__ unsigned short Vts[64][72];
    __shared__ unsigned short Ps [4][16][72];   // per-wave [q-col][s]

    const unsigned short* qb  = qkv + (size_t)b * T * 3072 + (h << 6);
    const unsigned short* kb  = qb + 1024;
    const unsigned short* vtb = vt + (size_t)bh * 64 * T;

    const int qw = q0 + w * 16;        // wave's first q row
    const int qg = qw + col;           // lane's q row

    // ---- Q B-frags: direct b128 loads (pre-scaled by log2e/8) ----
    short8 qf[2];
    {
        const unsigned short* qrow = qb + (size_t)qg * 3072 + (quad << 3);
        qf[0] = *(const short8*)&qrow[0];
        qf[1] = *(const short8*)&qrow[32];
    }

    f32x4 oacc[4];
    #pragma unroll
    for (int i = 0; i < 4; ++i) oacc[i] = (f32x4){0.f, 0.f, 0.f, 0.f};
    float l_i = 0.f;

    // ---- staging pointers + register prefetch of tile kt=0 ----
    const int sr = t >> 3, sc = (t & 7) << 3;   // 32 rows x 64 cols per pass
    const unsigned short* kp0 = kb  + (size_t)sr * 3072 + sc;
    const unsigned short* kp1 = kp0 + (size_t)32 * 3072;
    const unsigned short* vp0 = vtb + (size_t)sr * T + sc;
    const unsigned short* vp1 = vp0 + (size_t)32 * T;
    unsigned short* kw0 = &Ks[sr][sc];
    unsigned short* kw1 = &Ks[sr + 32][sc];
    unsigned short* vw0 = &Vts[sr][sc];
    unsigned short* vw1 = &Vts[sr + 32][sc];
    unsigned short* pw  = &Ps[w][col][0];

    short8 rk0 = *(const short8*)kp0;
    short8 rk1 = *(const short8*)kp1;
    short8 rv0 = *(const short8*)vp0;
    short8 rv1 = *(const short8*)vp1;

    const int last_kt = q0 >> 6;
    for (int kt = 0; kt <= last_kt; ++kt) {
        const int k0 = kt << 6;
        __syncthreads();   // prev compute done reading LDS
        *(short8*)kw0 = rk0;
        *(short8*)kw1 = rk1;
        *(short8*)vw0 = rv0;
        *(short8*)vw1 = rv1;
        __syncthreads();
        // prefetch next tile AFTER the barrier: loads fly during compute,
        // drained by next iteration's first barrier.
        if (kt < last_kt) {
            kp0 += 64 * 3072; kp1 += 64 * 3072; vp0 += 64; vp1 += 64;
            rk0 = *(const short8*)kp0;
            rk1 = *(const short8*)kp1;
            rv0 = *(const short8*)vp0;
            rv1 = *(const short8*)vp1;
        }

        // ---- S^T = K @ Q^T ----
        f32x4 st[4];
        #pragma unroll
        for (int i = 0; i < 4; ++i) st[i] = (f32x4){0.f, 0.f, 0.f, 0.f};
        #pragma unroll
        for (int ks = 0; ks < 2; ++ks)
            #pragma unroll
            for (int mt = 0; mt < 4; ++mt) {
                const short8 kf = *(const short8*)&Ks[mt * 16 + col][ks * 32 + (quad << 3)];
                st[mt] = __builtin_amdgcn_mfma_f32_16x16x32_bf16(kf, qf[ks], st[mt], 0, 0, 0);
            }

        // ---- fixed-max softmax: p = exp2(s), mask via exp2(-inf)=0 ----
        const bool diag = (k0 + 63 > qw);
        float rs = 0.f;
        #pragma unroll
        for (int mt = 0; mt < 4; ++mt) {
            float x0 = st[mt][0], x1 = st[mt][1], x2 = st[mt][2], x3 = st[mt][3];
            if (diag) {
                const int sbase = k0 + mt * 16 + (quad << 2);
                if (sbase + 0 > qg) x0 = -INFINITY;
                if (sbase + 1 > qg) x1 = -INFINITY;
                if (sbase + 2 > qg) x2 = -INFINITY;
                if (sbase + 3 > qg) x3 = -INFINITY;
            }
            const float p0 = __builtin_amdgcn_exp2f(x0);
            const float p1 = __builtin_amdgcn_exp2f(x1);
            const float p2 = __builtin_amdgcn_exp2f(x2);
            const float p3 = __builtin_amdgcn_exp2f(x3);
            rs += (p0 + p1) + (p2 + p3);
            uint2 pk;
            pk.x = pack_bf16_ru(p0, p1);
            pk.y = pack_bf16_ru(p2, p3);
            *(uint2*)&pw[mt * 16 + (quad << 2)] = pk;
        }
        rs += __shfl_xor(rs, 16, 64);
        rs += __shfl_xor(rs, 32, 64);
        l_i += rs;

        // ---- O^T += V^T @ P^T ----
        #pragma unroll
        for (int ks = 0; ks < 2; ++ks) {
            const short8 pf = *(const short8*)&pw[ks * 32 + (quad << 3)];
            #pragma unroll
            for (int mt = 0; mt < 4; ++mt) {
                const short8 vf = *(const short8*)&Vts[mt * 16 + col][ks * 32 + (quad << 3)];
                oacc[mt] = __builtin_amdgcn_mfma_f32_16x16x32_bf16(vf, pf, oacc[mt], 0, 0, 0);
            }
        }
    }

    // ---- epilogue: normalize, store y[b,t,h,d] (bf16) ----
    const float inv = 1.0f / l_i;
    unsigned short* yrow = yb + (size_t)(b * T + qg) * 1024 + (h << 6);
    #pragma unroll
    for (int mt = 0; mt < 4; ++mt) {
        ushort4 yv;
        yv.x = f2bf(oacc[mt][0] * inv);
        yv.y = f2bf(oacc[mt][1] * inv);
        yv.z = f2bf(oacc[mt][2] * inv);
        yv.w = f2bf(oacc[mt][3] * inv);
        *(ushort4*)&yrow[mt * 16 + (quad << 2)] = yv;
    }
}

// ======================================================================
extern "C" void kernel_launch(void* const* d_in, const int* in_sizes, int n_in,
                              void* d_out, int out_size, void* d_ws, size_t ws_size,
                              hipStream_t stream)
{
    const float* x      = (const float*)d_in[0];
    const float* cosp   = (const float*)d_in[1];
    const float* sinp   = (const float*)d_in[2];
    const float* W_attn = (const float*)d_in[3];
    const float* b_attn = (const float*)d_in[4];
    const float* W_proj = (const float*)d_in[5];
    const float* b_proj = (const float*)d_in[6];
    float* out = (float*)d_out;

    const int C = 1024, H = 16;
    const int T  = in_sizes[1] / 64;     // cos: (T, 64)
    const int BT = in_sizes[0] / C;      // B*T
    const int B  = BT / T;

    unsigned short* qkvb = (unsigned short*)d_ws;              // BT*3072
    unsigned short* xb   = qkvb + (size_t)BT * 3072;           // BT*1024
    unsigned short* Wab  = xb   + (size_t)BT * 1024;           // 3072*1024
    unsigned short* Wpb  = Wab  + (size_t)3072 * 1024;         // 1024*1024
    unsigned short* yb   = Wpb  + (size_t)1024 * 1024;         // BT*1024
    unsigned short* vtb  = xb;   // vt aliases xb (x dead after gemm1)

    cast_bf16<<<dim3(BT * C / 1024), dim3(256), 0, stream>>>(x, xb, BT * C);
    transpose_cast_both<<<dim3(128, 32), dim3(256), 0, stream>>>(
        W_attn, Wab, W_proj, Wpb);

    gemm_bf16<true><<<dim3(3 * C / 128, BT / 128), dim3(256), 0, stream>>>(
        xb, Wab, b_attn, qkvb, BT, 3 * C, C);

    rmsnorm_rope<<<dim3(BT * 2), dim3(256), 0, stream>>>(
        qkvb, cosp, sinp, BT, T);

    v_transpose<<<dim3(B * H, T / 64), dim3(256), 0, stream>>>(qkvb, vtb, T);

    flash_attn_mfma<<<dim3(B * H, T / 64), dim3(256), 0, stream>>>(
        qkvb, vtb, yb, B, T);

    gemm_bf16_n64<<<dim3(C / 64, BT / 128), dim3(256), 0, stream>>>(
        yb, Wpb, b_proj, out, BT, C, C);
}

// Round 10
// 192.508 us; speedup vs baseline: 1.2985x; 1.0517x over previous
//
#include <hip/hip_runtime.h>
#include <math.h>

#define EPSV 1.1920929e-07f

typedef __attribute__((ext_vector_type(8))) short short8;
typedef __attribute__((ext_vector_type(4))) float f32x4;

__device__ __forceinline__ float bf2f(unsigned short u) {
    union { unsigned int i; float f; } c; c.i = ((unsigned int)u) << 16; return c.f;
}
__device__ __forceinline__ unsigned short f2bf(float f) {
    union { float f; unsigned int i; } c; c.f = f;
    unsigned int r = c.i + 0x7FFFu + ((c.i >> 16) & 1u);   // RNE
    return (unsigned short)(r >> 16);
}
// pack two f32 -> two bf16 (round-half-up) in one u32: low=a, high=b
__device__ __forceinline__ unsigned int pack_bf16_ru(float a, float b) {
    union { float f; unsigned int i; } ca, cb; ca.f = a; cb.f = b;
    return __builtin_amdgcn_perm(cb.i + 0x8000u, ca.i + 0x8000u, 0x07060302u);
}
// async global -> LDS, 16 B per lane (dest = wave-uniform base + lane*16)
__device__ __forceinline__ void async_lds16(const unsigned short* g, unsigned short* l) {
    __builtin_amdgcn_global_load_lds(
        (const __attribute__((address_space(1))) unsigned int*)g,
        (__attribute__((address_space(3))) unsigned int*)l, 16, 0, 0);
}

// ======================================================================
// cast fp32 -> bf16 elementwise. 4 elems/thread.
// ======================================================================
__global__ __launch_bounds__(256) void cast_bf16(
    const float* __restrict__ src, unsigned short* __restrict__ dst, int n)
{
    const int i = (blockIdx.x * 256 + threadIdx.x) * 4;
    if (i >= n) return;
    const float4 v = *(const float4*)&src[i];
    ushort4 o;
    o.x = f2bf(v.x); o.y = f2bf(v.y); o.z = f2bf(v.z); o.w = f2bf(v.w);
    *(ushort4*)&dst[i] = o;
}

// ======================================================================
// transpose + cast for BOTH weights in one launch:
// W_attn [1024][3072] -> Wat [3072][1024]; W_proj [1024][1024] -> Wpt.
// ======================================================================
__global__ __launch_bounds__(256) void transpose_cast_both(
    const float* __restrict__ Wa, unsigned short* __restrict__ Wat,
    const float* __restrict__ Wp, unsigned short* __restrict__ Wpt)
{
    __shared__ float tile[32][33];
    int bx = blockIdx.x;
    const float* W; unsigned short* Wt; int N;
    if (bx < 96) { W = Wa; Wt = Wat; N = 3072; }
    else         { W = Wp; Wt = Wpt; N = 1024; bx -= 96; }
    const int n0 = bx * 32, k0 = blockIdx.y * 32;
    const int r = threadIdx.x >> 3, c4 = (threadIdx.x & 7) * 4;
    const float4 v = *(const float4*)&W[(size_t)(k0 + r) * N + n0 + c4];
    tile[r][c4 + 0] = v.x; tile[r][c4 + 1] = v.y;
    tile[r][c4 + 2] = v.z; tile[r][c4 + 3] = v.w;
    __syncthreads();
    ushort4 o;
    o.x = f2bf(tile[c4 + 0][r]); o.y = f2bf(tile[c4 + 1][r]);
    o.z = f2bf(tile[c4 + 2][r]); o.w = f2bf(tile[c4 + 3][r]);
    *(ushort4*)&Wt[(size_t)(n0 + r) * 1024 + k0 + c4] = o;
}

// ======================================================================
// bf16 MFMA GEMM, m97 structure + BK=64 (paired half-K buffers so the
// unpadded [128][32] layout / global_load_lds constraint is preserved;
// barriers per MFMA halved vs BK=32). C = A @ Bt^T + bias.
// LDS 32 KB -> 5 blocks/CU capacity (grid-limited at 3, unchanged).
// ======================================================================
template <bool OUT_BF16>
__global__ __launch_bounds__(256) void gemm_bf16(
    const unsigned short* __restrict__ A,
    const unsigned short* __restrict__ Bt,
    const float* __restrict__ bias,
    void* __restrict__ Cv,
    int M, int N, int K)
{
    __shared__ unsigned short As0[128][32], As1[128][32];
    __shared__ unsigned short Bs0[128][32], Bs1[128][32];
    const int t    = threadIdx.x;
    const int lane = t & 63;
    const int wv   = t >> 6;
    const int wrow = (wv >> 1) * 64;
    const int wcol = (wv & 1) * 64;
    const int m0 = blockIdx.y * 128;
    const int n0 = blockIdx.x * 128;
    const int col  = lane & 15;
    const int quad = lane >> 4;

    const int srow = (wv << 5) + (lane >> 2);     // wv*32 + 0..15
    const int scol = (lane & 3) << 3;             // 0,8,16,24
    // A/B pointers: [row block 0/16][k-half 0/32]
    const unsigned short* a00 = A  + (size_t)(m0 + srow) * K + scol;
    const unsigned short* a10 = a00 + (size_t)16 * K;
    const unsigned short* a01 = a00 + 32;
    const unsigned short* a11 = a10 + 32;
    const unsigned short* b00 = Bt + (size_t)(n0 + srow) * K + scol;
    const unsigned short* b10 = b00 + (size_t)16 * K;
    const unsigned short* b01 = b00 + 32;
    const unsigned short* b11 = b10 + 32;
    unsigned short* al0 = &As0[srow][scol];
    unsigned short* al1 = &As0[srow + 16][scol];
    unsigned short* al2 = &As1[srow][scol];
    unsigned short* al3 = &As1[srow + 16][scol];
    unsigned short* bl0 = &Bs0[srow][scol];
    unsigned short* bl1 = &Bs0[srow + 16][scol];
    unsigned short* bl2 = &Bs1[srow][scol];
    unsigned short* bl3 = &Bs1[srow + 16][scol];

    f32x4 acc[4][4];
    #pragma unroll
    for (int i = 0; i < 4; ++i)
        #pragma unroll
        for (int j = 0; j < 4; ++j)
            acc[i][j] = (f32x4){0.f, 0.f, 0.f, 0.f};

    for (int k0 = 0; k0 < K; k0 += 64) {
        async_lds16(a00, al0);
        async_lds16(a10, al1);
        async_lds16(a01, al2);
        async_lds16(a11, al3);
        async_lds16(b00, bl0);
        async_lds16(b10, bl1);
        async_lds16(b01, bl2);
        async_lds16(b11, bl3);
        a00 += 64; a10 += 64; a01 += 64; a11 += 64;
        b00 += 64; b10 += 64; b01 += 64; b11 += 64;
        __syncthreads();
        short8 af[2][4], bf[2][4];
        #pragma unroll
        for (int mt = 0; mt < 4; ++mt) {
            af[0][mt] = *(const short8*)&As0[wrow + mt * 16 + col][quad << 3];
            af[1][mt] = *(const short8*)&As1[wrow + mt * 16 + col][quad << 3];
        }
        #pragma unroll
        for (int nt = 0; nt < 4; ++nt) {
            bf[0][nt] = *(const short8*)&Bs0[wcol + nt * 16 + col][quad << 3];
            bf[1][nt] = *(const short8*)&Bs1[wcol + nt * 16 + col][quad << 3];
        }
        #pragma unroll
        for (int ks = 0; ks < 2; ++ks)
            #pragma unroll
            for (int mt = 0; mt < 4; ++mt)
                #pragma unroll
                for (int nt = 0; nt < 4; ++nt)
                    acc[mt][nt] = __builtin_amdgcn_mfma_f32_16x16x32_bf16(
                        af[ks][mt], bf[ks][nt], acc[mt][nt], 0, 0, 0);
        __syncthreads();
    }

    const int rowq = quad << 2;
    #pragma unroll
    for (int nt = 0; nt < 4; ++nt) {
        const int n = n0 + wcol + nt * 16 + col;
        const float bv = bias[n];
        #pragma unroll
        for (int mt = 0; mt < 4; ++mt) {
            #pragma unroll
            for (int r = 0; r < 4; ++r) {
                const int m = m0 + wrow + mt * 16 + rowq + r;
                const float v = acc[mt][nt][r] + bv;
                if (OUT_BF16)
                    ((unsigned short*)Cv)[(size_t)m * N + n] = f2bf(v);
                else
                    ((float*)Cv)[(size_t)m * N + n] = v;
            }
        }
    }
}

// ======================================================================
// bf16 MFMA GEMM, 128(M) x 64(N), BK=64 (skinny-N gemm2). fp32 out.
// ======================================================================
__global__ __launch_bounds__(256) void gemm_bf16_n64(
    const unsigned short* __restrict__ A,
    const unsigned short* __restrict__ Bt,
    const float* __restrict__ bias,
    float* __restrict__ C,
    int M, int N, int K)
{
    __shared__ unsigned short As0[128][32], As1[128][32];
    __shared__ unsigned short Bs0[64][32], Bs1[64][32];
    const int t    = threadIdx.x;
    const int lane = t & 63;
    const int wv   = t >> 6;
    const int wrow = wv << 5;
    const int m0 = blockIdx.y * 128;
    const int n0 = blockIdx.x * 64;
    const int col  = lane & 15;
    const int quad = lane >> 4;

    const int srow = (wv << 5) + (lane >> 2);
    const int scol = (lane & 3) << 3;
    const unsigned short* a00 = A  + (size_t)(m0 + srow) * K + scol;
    const unsigned short* a10 = a00 + (size_t)16 * K;
    const unsigned short* a01 = a00 + 32;
    const unsigned short* a11 = a10 + 32;
    const int bsrow = (wv << 4) + (lane >> 2);
    const unsigned short* b00 = Bt + (size_t)(n0 + bsrow) * K + scol;
    const unsigned short* b01 = b00 + 32;
    unsigned short* al0 = &As0[srow][scol];
    unsigned short* al1 = &As0[srow + 16][scol];
    unsigned short* al2 = &As1[srow][scol];
    unsigned short* al3 = &As1[srow + 16][scol];
    unsigned short* bl0 = &Bs0[bsrow][scol];
    unsigned short* bl1 = &Bs1[bsrow][scol];

    f32x4 acc[2][4];
    #pragma unroll
    for (int i = 0; i < 2; ++i)
        #pragma unroll
        for (int j = 0; j < 4; ++j)
            acc[i][j] = (f32x4){0.f, 0.f, 0.f, 0.f};

    for (int k0 = 0; k0 < K; k0 += 64) {
        async_lds16(a00, al0);
        async_lds16(a10, al1);
        async_lds16(a01, al2);
        async_lds16(a11, al3);
        async_lds16(b00, bl0);
        async_lds16(b01, bl1);
        a00 += 64; a10 += 64; a01 += 64; a11 += 64;
        b00 += 64; b01 += 64;
        __syncthreads();
        short8 af[2][2], bf[2][4];
        #pragma unroll
        for (int mt = 0; mt < 2; ++mt) {
            af[0][mt] = *(const short8*)&As0[wrow + mt * 16 + col][quad << 3];
            af[1][mt] = *(const short8*)&As1[wrow + mt * 16 + col][quad << 3];
        }
        #pragma unroll
        for (int nt = 0; nt < 4; ++nt) {
            bf[0][nt] = *(const short8*)&Bs0[nt * 16 + col][quad << 3];
            bf[1][nt] = *(const short8*)&Bs1[nt * 16 + col][quad << 3];
        }
        #pragma unroll
        for (int ks = 0; ks < 2; ++ks)
            #pragma unroll
            for (int mt = 0; mt < 2; ++mt)
                #pragma unroll
                for (int nt = 0; nt < 4; ++nt)
                    acc[mt][nt] = __builtin_amdgcn_mfma_f32_16x16x32_bf16(
                        af[ks][mt], bf[ks][nt], acc[mt][nt], 0, 0, 0);
        __syncthreads();
    }

    const int rowq = quad << 2;
    #pragma unroll
    for (int nt = 0; nt < 4; ++nt) {
        const int n = n0 + nt * 16 + col;
        const float bv = bias[n];
        #pragma unroll
        for (int mt = 0; mt < 2; ++mt) {
            #pragma unroll
            for (int r = 0; r < 4; ++r) {
                const int m = m0 + wrow + mt * 16 + rowq + r;
                C[(size_t)m * N + n] = acc[mt][nt][r] + bv;
            }
        }
    }
}

// ======================================================================
// RMSNorm (D=64) then rotary, in-place on bf16 q/k slices.
// 4 rows per wave: 16 lanes per row, ushort4/float4 vector loads.
// q output pre-scaled by log2e/8 (folds softmax scale -> exp2 domain).
// ======================================================================
__global__ __launch_bounds__(256) void rmsnorm_rope(
    unsigned short* __restrict__ qkv, const float* __restrict__ cosp,
    const float* __restrict__ sinp, int BT, int T)
{
    const int wid  = (blockIdx.x << 2) + (threadIdx.x >> 6);
    const int lane = threadIdx.x & 63;
    const int hq = wid & 3;
    const int w  = (wid >> 2) & 1;
    const int bt = wid >> 3;
    if (bt >= BT) return;
    const int h  = (hq << 2) + (lane >> 4);
    const int d4 = (lane & 15) << 2;
    const int tpos = bt % T;
    const size_t idx = (size_t)bt * 3072 + (w << 10) + (h << 6) + d4;

    const ushort4 u = *(const ushort4*)&qkv[idx];
    const float x0 = bf2f(u.x), x1 = bf2f(u.y), x2 = bf2f(u.z), x3 = bf2f(u.w);
    float ss = x0 * x0 + x1 * x1 + x2 * x2 + x3 * x3;
    ss += __shfl_xor(ss, 1, 64);
    ss += __shfl_xor(ss, 2, 64);
    ss += __shfl_xor(ss, 4, 64);
    ss += __shfl_xor(ss, 8, 64);
    const float rn = rsqrtf(ss * (1.0f / 64.0f) + EPSV);
    const float xn0 = x0 * rn, xn1 = x1 * rn, xn2 = x2 * rn, xn3 = x3 * rn;
    const float p0 = __shfl_xor(xn0, 8, 64);
    const float p1 = __shfl_xor(xn1, 8, 64);
    const float p2 = __shfl_xor(xn2, 8, 64);
    const float p3 = __shfl_xor(xn3, 8, 64);
    const float sgn = (d4 < 32) ? -1.0f : 1.0f;
    const float4 c = *(const float4*)&cosp[tpos * 64 + d4];
    const float4 s = *(const float4*)&sinp[tpos * 64 + d4];
    const float scale = (w == 0) ? 0.18033688011112042f : 1.0f;  // log2e/8
    ushort4 o;
    o.x = f2bf(fmaf(xn0, c.x, sgn * p0 * s.x) * scale);
    o.y = f2bf(fmaf(xn1, c.y, sgn * p1 * s.y) * scale);
    o.z = f2bf(fmaf(xn2, c.z, sgn * p2 * s.z) * scale);
    o.w = f2bf(fmaf(xn3, c.w, sgn * p3 * s.w) * scale);
    *(ushort4*)&qkv[idx] = o;
}

// ======================================================================
// V transpose: qkv v-slice [b,t,h,d] -> vt [b,h,d,t]. 64x64 tiles.
// ======================================================================
__global__ __launch_bounds__(256) void v_transpose(
    const unsigned short* __restrict__ qkv, unsigned short* __restrict__ vt,
    int T)
{
    __shared__ unsigned short tile[64][72];
    const int bh = blockIdx.x;
    const int b  = bh >> 4, h = bh & 15;
    const int t0 = blockIdx.y << 6;
    const int t  = threadIdx.x;
    const unsigned short* vbase = qkv + (size_t)b * T * 3072 + 2048 + (h << 6);

    #pragma unroll
    for (int i = 0; i < 2; ++i) {
        const int c = t + (i << 8);
        const int r = c >> 3, c8 = (c & 7) << 3;
        const short8 v = *(const short8*)&vbase[(size_t)(t0 + r) * 3072 + c8];
        #pragma unroll
        for (int j = 0; j < 8; ++j)
            tile[c8 + j][r] = (unsigned short)v[j];
    }
    __syncthreads();
    #pragma unroll
    for (int i = 0; i < 2; ++i) {
        const int c = t + (i << 8);
        const int d = c >> 3, c8 = (c & 7) << 3;
        const short8 o = *(const short8*)&tile[d][c8];
        *(short8*)&vt[((size_t)bh * 64 + d) * T + t0 + c8] = o;
    }
}

// ======================================================================
// MFMA flash attention, FIXED-MAX softmax (no online rescaling):
// rms_norm bounds |q^.k^| <= 64, so s*log2e/8 <= 11.6 and p = exp2(s)
// can never overflow fp32 -- no running max, no alpha, no max shuffles.
// Block = (b,h) x 64 q-rows, 4 waves; K/V^T staged in LDS; next tile
// register-prefetched after the 2nd barrier (overlaps compute).
// ======================================================================
__global__ __launch_bounds__(256) void flash_attn_mfma(
    const unsigned short* __restrict__ qkv,
    const unsigned short* __restrict__ vt,
    unsigned short* __restrict__ yb,
    int B, int T)
{
    const int bh = blockIdx.x;
    const int b  = bh >> 4, h = bh & 15;
    const int q0 = ((int)gridDim.y - 1 - (int)blockIdx.y) << 6;  // heavy first
    const int t  = threadIdx.x;
    const int lane = t & 63;
    const int w    = t >> 6;
    const int col  = lane & 15;
    const int quad = lane >> 4;

    __shared__ unsigned short Ks [64][72];
    __shared__ unsigned short Vts[64][72];
    __shared__ unsigned short Ps [4][16][72];   // per-wave [q-col][s]

    const unsigned short* qb  = qkv + (size_t)b * T * 3072 + (h << 6);
    const unsigned short* kb  = qb + 1024;
    const unsigned short* vtb = vt + (size_t)bh * 64 * T;

    const int qw = q0 + w * 16;        // wave's first q row
    const int qg = qw + col;           // lane's q row

    short8 qf[2];
    {
        const unsigned short* qrow = qb + (size_t)qg * 3072 + (quad << 3);
        qf[0] = *(const short8*)&qrow[0];
        qf[1] = *(const short8*)&qrow[32];
    }

    f32x4 oacc[4];
    #pragma unroll
    for (int i = 0; i < 4; ++i) oacc[i] = (f32x4){0.f, 0.f, 0.f, 0.f};
    float l_i = 0.f;

    const int sr = t >> 3, sc = (t & 7) << 3;   // 32 rows x 64 cols per pass
    const unsigned short* kp0 = kb  + (size_t)sr * 3072 + sc;
    const unsigned short* kp1 = kp0 + (size_t)32 * 3072;
    const unsigned short* vp0 = vtb + (size_t)sr * T + sc;
    const unsigned short* vp1 = vp0 + (size_t)32 * T;
    unsigned short* kw0 = &Ks[sr][sc];
    unsigned short* kw1 = &Ks[sr + 32][sc];
    unsigned short* vw0 = &Vts[sr][sc];
    unsigned short* vw1 = &Vts[sr + 32][sc];
    unsigned short* pw  = &Ps[w][col][0];

    short8 rk0 = *(const short8*)kp0;
    short8 rk1 = *(const short8*)kp1;
    short8 rv0 = *(const short8*)vp0;
    short8 rv1 = *(const short8*)vp1;

    const int last_kt = q0 >> 6;
    for (int kt = 0; kt <= last_kt; ++kt) {
        const int k0 = kt << 6;
        __syncthreads();   // prev compute done reading LDS
        *(short8*)kw0 = rk0;
        *(short8*)kw1 = rk1;
        *(short8*)vw0 = rv0;
        *(short8*)vw1 = rv1;
        __syncthreads();
        if (kt < last_kt) {
            kp0 += 64 * 3072; kp1 += 64 * 3072; vp0 += 64; vp1 += 64;
            rk0 = *(const short8*)kp0;
            rk1 = *(const short8*)kp1;
            rv0 = *(const short8*)vp0;
            rv1 = *(const short8*)vp1;
        }

        // ---- S^T = K @ Q^T ----
        f32x4 st[4];
        #pragma unroll
        for (int i = 0; i < 4; ++i) st[i] = (f32x4){0.f, 0.f, 0.f, 0.f};
        #pragma unroll
        for (int ks = 0; ks < 2; ++ks)
            #pragma unroll
            for (int mt = 0; mt < 4; ++mt) {
                const short8 kf = *(const short8*)&Ks[mt * 16 + col][ks * 32 + (quad << 3)];
                st[mt] = __builtin_amdgcn_mfma_f32_16x16x32_bf16(kf, qf[ks], st[mt], 0, 0, 0);
            }

        // ---- fixed-max softmax: p = exp2(s), mask via exp2(-inf)=0 ----
        const bool diag = (k0 + 63 > qw);
        float rs = 0.f;
        #pragma unroll
        for (int mt = 0; mt < 4; ++mt) {
            float x0 = st[mt][0], x1 = st[mt][1], x2 = st[mt][2], x3 = st[mt][3];
            if (diag) {
                const int sbase = k0 + mt * 16 + (quad << 2);
                if (sbase + 0 > qg) x0 = -INFINITY;
                if (sbase + 1 > qg) x1 = -INFINITY;
                if (sbase + 2 > qg) x2 = -INFINITY;
                if (sbase + 3 > qg) x3 = -INFINITY;
            }
            const float p0 = __builtin_amdgcn_exp2f(x0);
            const float p1 = __builtin_amdgcn_exp2f(x1);
            const float p2 = __builtin_amdgcn_exp2f(x2);
            const float p3 = __builtin_amdgcn_exp2f(x3);
            rs += (p0 + p1) + (p2 + p3);
            uint2 pk;
            pk.x = pack_bf16_ru(p0, p1);
            pk.y = pack_bf16_ru(p2, p3);
            *(uint2*)&pw[mt * 16 + (quad << 2)] = pk;
        }
        rs += __shfl_xor(rs, 16, 64);
        rs += __shfl_xor(rs, 32, 64);
        l_i += rs;

        // ---- O^T += V^T @ P^T ----
        #pragma unroll
        for (int ks = 0; ks < 2; ++ks) {
            const short8 pf = *(const short8*)&pw[ks * 32 + (quad << 3)];
            #pragma unroll
            for (int mt = 0; mt < 4; ++mt) {
                const short8 vf = *(const short8*)&Vts[mt * 16 + col][ks * 32 + (quad << 3)];
                oacc[mt] = __builtin_amdgcn_mfma_f32_16x16x32_bf16(vf, pf, oacc[mt], 0, 0, 0);
            }
        }
    }

    // ---- epilogue: normalize, store y[b,t,h,d] (bf16) ----
    const float inv = 1.0f / l_i;
    unsigned short* yrow = yb + (size_t)(b * T + qg) * 1024 + (h << 6);
    #pragma unroll
    for (int mt = 0; mt < 4; ++mt) {
        ushort4 yv;
        yv.x = f2bf(oacc[mt][0] * inv);
        yv.y = f2bf(oacc[mt][1] * inv);
        yv.z = f2bf(oacc[mt][2] * inv);
        yv.w = f2bf(oacc[mt][3] * inv);
        *(ushort4*)&yrow[mt * 16 + (quad << 2)] = yv;
    }
}

// ======================================================================
extern "C" void kernel_launch(void* const* d_in, const int* in_sizes, int n_in,
                              void* d_out, int out_size, void* d_ws, size_t ws_size,
                              hipStream_t stream)
{
    const float* x      = (const float*)d_in[0];
    const float* cosp   = (const float*)d_in[1];
    const float* sinp   = (const float*)d_in[2];
    const float* W_attn = (const float*)d_in[3];
    const float* b_attn = (const float*)d_in[4];
    const float* W_proj = (const float*)d_in[5];
    const float* b_proj = (const float*)d_in[6];
    float* out = (float*)d_out;

    const int C = 1024, H = 16;
    const int T  = in_sizes[1] / 64;     // cos: (T, 64)
    const int BT = in_sizes[0] / C;      // B*T
    const int B  = BT / T;

    unsigned short* qkvb = (unsigned short*)d_ws;              // BT*3072
    unsigned short* xb   = qkvb + (size_t)BT * 3072;           // BT*1024
    unsigned short* Wab  = xb   + (size_t)BT * 1024;           // 3072*1024
    unsigned short* Wpb  = Wab  + (size_t)3072 * 1024;         // 1024*1024
    unsigned short* yb   = Wpb  + (size_t)1024 * 1024;         // BT*1024
    unsigned short* vtb  = xb;   // vt aliases xb (x dead after gemm1)

    cast_bf16<<<dim3(BT * C / 1024), dim3(256), 0, stream>>>(x, xb, BT * C);
    transpose_cast_both<<<dim3(128, 32), dim3(256), 0, stream>>>(
        W_attn, Wab, W_proj, Wpb);

    gemm_bf16<true><<<dim3(3 * C / 128, BT / 128), dim3(256), 0, stream>>>(
        xb, Wab, b_attn, qkvb, BT, 3 * C, C);

    rmsnorm_rope<<<dim3(BT * 2), dim3(256), 0, stream>>>(
        qkvb, cosp, sinp, BT, T);

    v_transpose<<<dim3(B * H, T / 64), dim3(256), 0, stream>>>(qkvb, vtb, T);

    flash_attn_mfma<<<dim3(B * H, T / 64), dim3(256), 0, stream>>>(
        qkvb, vtb, yb, B, T);

    gemm_bf16_n64<<<dim3(C / 64, BT / 128), dim3(256), 0, stream>>>(
        yb, Wpb, b_proj, out, BT, C, C);
}